// Round 7
// baseline (5702.293 us; speedup 1.0000x reference)
//
#include <hip/hip_runtime.h>
#include <hip/hip_bf16.h>
#include <cstdint>
#include <cstddef>

#define B_   128
#define T_   256
#define TC_  64     // time-chunk length (xg computed per chunk)
#define H_   512
#define G_   1536   // 3*H
#define DIN_ 1024

// ---------------- prep: k-major float4 repack of w_hh and fc_mid_w ----------------
// W4hh[k4][row] = w_hh[row][4k4..4k4+3]   (k4 in [0,128), row in [0,1536))
// W4fc[k4][col] = fc_mid_w[col][4k4..4k4+3]
__global__ __launch_bounds__(256) void k_prep(const float* __restrict__ w_hh,
                                              const float* __restrict__ fc_mid_w,
                                              float4* __restrict__ W4hh,
                                              float4* __restrict__ W4fc)
{
    int tid = blockIdx.x * 256 + threadIdx.x;
    if (tid < 128 * G_) {
        int k4 = tid / G_;
        int r  = tid - k4 * G_;
        const float* s = w_hh + (size_t)r * H_ + k4 * 4;
        W4hh[tid] = make_float4(s[0], s[1], s[2], s[3]);
    }
    if (tid < 128 * H_) {
        int k4 = tid / H_;
        int c  = tid - k4 * H_;
        const float* s = fc_mid_w + (size_t)c * H_ + k4 * 4;
        W4fc[tid] = make_float4(s[0], s[1], s[2], s[3]);
    }
}

// ---------------- K1: xg chunk GEMM ----------------
// For time-chunk starting at c0: xgc[b*64 + tc][g] =
//   concat(H,C)[b][c0+tc][:] . w_ih[g][:] + b_ih[g]
// fp32 tiled GEMM, 128x128 block tile, 8x8 per thread, BK=16.
// grid: (12, 64)  [G_/128 x 8192/128]
__global__ __launch_bounds__(256) void k_xg(const float* __restrict__ Hin,
                                            const float* __restrict__ Ce,
                                            const float* __restrict__ w_ih,
                                            const float* __restrict__ b_ih,
                                            float* __restrict__ xgc,
                                            const int c0)
{
    __shared__ float As[16][132];
    __shared__ float Bs[16][132];
    const int tid = threadIdx.x;
    const int n0 = blockIdx.x * 128;   // over G_=1536 -> 12 blocks
    const int m0 = blockIdx.y * 128;   // over 8192 chunk rows -> 64 blocks
    const int tx = tid & 15;
    const int ty = tid >> 4;
    const int lr = tid >> 2;           // 0..63
    const int lk = (tid & 3) * 4;      // 0,4,8,12

    float acc[8][8];
    #pragma unroll
    for (int i = 0; i < 8; ++i)
        #pragma unroll
        for (int j = 0; j < 8; ++j) acc[i][j] = 0.f;

    for (int k0 = 0; k0 < DIN_; k0 += 16) {
        const bool first = (k0 < 512);
        #pragma unroll
        for (int h = 0; h < 2; ++h) {
            int mr   = lr + h * 64;
            int mr_g = m0 + mr;                 // chunk row
            int b    = mr_g >> 6;
            int tc   = mr_g & 63;
            size_t row = (size_t)b * T_ + c0 + tc;
            const float* src = first ? (Hin + row * 512 + (k0 + lk))
                                     : (Ce  + row * 512 + (k0 - 512 + lk));
            float4 v = *reinterpret_cast<const float4*>(src);
            As[lk + 0][mr] = v.x;
            As[lk + 1][mr] = v.y;
            As[lk + 2][mr] = v.z;
            As[lk + 3][mr] = v.w;
        }
        #pragma unroll
        for (int h = 0; h < 2; ++h) {
            int nr = lr + h * 64;
            const float* src = w_ih + (size_t)(n0 + nr) * DIN_ + k0 + lk;
            float4 v = *reinterpret_cast<const float4*>(src);
            Bs[lk + 0][nr] = v.x;
            Bs[lk + 1][nr] = v.y;
            Bs[lk + 2][nr] = v.z;
            Bs[lk + 3][nr] = v.w;
        }
        __syncthreads();
        #pragma unroll
        for (int kk = 0; kk < 16; ++kk) {
            float a[8], b[8];
            *reinterpret_cast<float4*>(&a[0]) = *reinterpret_cast<const float4*>(&As[kk][ty * 8]);
            *reinterpret_cast<float4*>(&a[4]) = *reinterpret_cast<const float4*>(&As[kk][ty * 8 + 4]);
            *reinterpret_cast<float4*>(&b[0]) = *reinterpret_cast<const float4*>(&Bs[kk][tx * 8]);
            *reinterpret_cast<float4*>(&b[4]) = *reinterpret_cast<const float4*>(&Bs[kk][tx * 8 + 4]);
            #pragma unroll
            for (int i = 0; i < 8; ++i)
                #pragma unroll
                for (int j = 0; j < 8; ++j)
                    acc[i][j] = fmaf(a[i], b[j], acc[i][j]);
        }
        __syncthreads();
    }

    float4 bv0 = *reinterpret_cast<const float4*>(b_ih + n0 + tx * 8);
    float4 bv1 = *reinterpret_cast<const float4*>(b_ih + n0 + tx * 8 + 4);
    #pragma unroll
    for (int i = 0; i < 8; ++i) {
        size_t m = (size_t)(m0 + ty * 8 + i);
        float* dst = xgc + m * G_ + n0 + tx * 8;
        *reinterpret_cast<float4*>(dst) =
            make_float4(acc[i][0] + bv0.x, acc[i][1] + bv0.y, acc[i][2] + bv0.z, acc[i][3] + bv0.w);
        *reinterpret_cast<float4*>(dst + 4) =
            make_float4(acc[i][4] + bv1.x, acc[i][5] + bv1.y, acc[i][6] + bv1.z, acc[i][7] + bv1.w);
    }
}

// ---------------- K2: one GRU timestep ----------------
// grid (32 j-chunks, 8 batch-groups); block 256 thr = (16 j) x (16 b).
// Reads h(t-1) rows from h_all, writes h(t) rows to h_all.
// xgc holds the current time-chunk; row index uses (t & 63).
__global__ __launch_bounds__(256) void k_step(const float4* __restrict__ W4hh,
                                              const float* __restrict__ b_hh,
                                              const float* __restrict__ xgc,
                                              float* __restrict__ h_all,
                                              const int t)
{
    __shared__ float hs[16][520];   // 16 batches x 512 (padded) = 33 KB
    const int tid = threadIdx.x;
    const int j0 = blockIdx.x * 16;
    const int b0 = blockIdx.y * 16;

    if (t > 0) {
        #pragma unroll
        for (int i = 0; i < 8; ++i) {
            int idx = i * 256 + tid;
            int bl = idx >> 7;
            int p  = (idx & 127) * 4;
            float4 v = *reinterpret_cast<const float4*>(
                h_all + ((size_t)(b0 + bl) * T_ + (t - 1)) * H_ + p);
            *reinterpret_cast<float4*>(&hs[bl][p]) = v;
        }
    } else {
        #pragma unroll
        for (int i = 0; i < 8; ++i) {
            int idx = i * 256 + tid;
            int bl = idx >> 7;
            int p  = (idx & 127) * 4;
            *reinterpret_cast<float4*>(&hs[bl][p]) = make_float4(0.f, 0.f, 0.f, 0.f);
        }
    }
    __syncthreads();

    const int jl = tid & 15;
    const int bl = tid >> 4;
    const int j  = j0 + jl;

    float ar = 0.f, az = 0.f, an = 0.f;
    const float4* wp = W4hh + j;          // + k4*G_ walks k
    const float* hrow = hs[bl];
    #pragma unroll 4
    for (int k4 = 0; k4 < 128; ++k4) {
        float4 h4 = *reinterpret_cast<const float4*>(hrow + k4 * 4);
        float4 w0 = wp[(size_t)k4 * G_];
        float4 w1 = wp[(size_t)k4 * G_ + 512];
        float4 w2 = wp[(size_t)k4 * G_ + 1024];
        ar = fmaf(w0.x, h4.x, fmaf(w0.y, h4.y, fmaf(w0.z, h4.z, fmaf(w0.w, h4.w, ar))));
        az = fmaf(w1.x, h4.x, fmaf(w1.y, h4.y, fmaf(w1.z, h4.z, fmaf(w1.w, h4.w, az))));
        an = fmaf(w2.x, h4.x, fmaf(w2.y, h4.y, fmaf(w2.z, h4.z, fmaf(w2.w, h4.w, an))));
    }

    float hr = ar + b_hh[j];
    float hz = az + b_hh[512 + j];
    float hn = an + b_hh[1024 + j];
    size_t mx = (size_t)(b0 + bl) * TC_ + (t & 63);    // row in xg chunk
    const float* xgm = xgc + mx * G_;
    float xr = xgm[j], xz = xgm[512 + j], xn = xgm[1024 + j];
    float r = 1.f / (1.f + expf(-(xr + hr)));
    float z = 1.f / (1.f + expf(-(xz + hz)));
    float n = tanhf(xn + r * hn);
    float hp = hrow[j];                    // zeros at t==0
    h_all[((size_t)(b0 + bl) * T_ + t) * H_ + j] = (1.f - z) * n + z * hp;
}

// ---------------- K3: fc_mid GEMM + LayerNorm + fc, fused ----------------
// Block = 16 rows of h_all; 256 threads; each thread 2 output cols.
// LN+fc collapse to per-row sums: logit = rstd*(Sgy - mu*Sgw) + Sbw + fc_b.
// LDS tile reused for h then y (33 KB total).
__global__ __launch_bounds__(256) void k_head(const float* __restrict__ h_all,
                                              const float4* __restrict__ W4fc,
                                              const float* __restrict__ fc_mid_b,
                                              const float* __restrict__ ln_g,
                                              const float* __restrict__ ln_b,
                                              const float* __restrict__ fc_w,
                                              const float* __restrict__ fc_b,
                                              float* __restrict__ out)
{
    __shared__ float hsm[16][520];
    const int tid = threadIdx.x;
    const size_t r0 = (size_t)blockIdx.x * 16;

    #pragma unroll
    for (int i = 0; i < 8; ++i) {
        int idx = i * 256 + tid;
        int rl = idx >> 7;
        int p  = (idx & 127) * 4;
        *reinterpret_cast<float4*>(&hsm[rl][p]) =
            *reinterpret_cast<const float4*>(h_all + (r0 + rl) * H_ + p);
    }
    __syncthreads();

    float accA[16], accB[16];
    #pragma unroll
    for (int i = 0; i < 16; ++i) { accA[i] = 0.f; accB[i] = 0.f; }
    const int cA = tid, cB = tid + 256;
    for (int k4 = 0; k4 < 128; ++k4) {
        float4 wA = W4fc[k4 * 512 + cA];
        float4 wB = W4fc[k4 * 512 + cB];
        #pragma unroll
        for (int rr = 0; rr < 16; ++rr) {
            float4 h4 = *reinterpret_cast<const float4*>(&hsm[rr][k4 * 4]);
            accA[rr] = fmaf(wA.x, h4.x, fmaf(wA.y, h4.y, fmaf(wA.z, h4.z, fmaf(wA.w, h4.w, accA[rr]))));
            accB[rr] = fmaf(wB.x, h4.x, fmaf(wB.y, h4.y, fmaf(wB.z, h4.z, fmaf(wB.w, h4.w, accB[rr]))));
        }
    }
    __syncthreads();   // everyone done READING hsm -> safe to overwrite with y
    const float bA = fc_mid_b[cA], bB = fc_mid_b[cB];
    #pragma unroll
    for (int rr = 0; rr < 16; ++rr) {
        hsm[rr][cA] = accA[rr] + bA;
        hsm[rr][cB] = accB[rr] + bB;
    }
    __syncthreads();

    const int lane = tid & 63;
    const int wv   = tid >> 6;
    float gw[8];
    float sgw = 0.f, sbw = 0.f;
    #pragma unroll
    for (int i = 0; i < 8; ++i) {
        int c = lane + i * 64;
        float g = ln_g[c], w = fc_w[c];
        gw[i] = g * w;
        sgw += gw[i];
        sbw += ln_b[c] * w;
    }
    #pragma unroll
    for (int off = 32; off; off >>= 1) {
        sgw += __shfl_xor(sgw, off);
        sbw += __shfl_xor(sbw, off);
    }
    const float fcb0 = fc_b[0];
    for (int rr = wv; rr < 16; rr += 4) {
        float s1 = 0.f, s2 = 0.f, sg = 0.f;
        #pragma unroll
        for (int i = 0; i < 8; ++i) {
            float y = hsm[rr][lane + i * 64];
            s1 += y; s2 += y * y; sg += gw[i] * y;
        }
        #pragma unroll
        for (int off = 32; off; off >>= 1) {
            s1 += __shfl_xor(s1, off);
            s2 += __shfl_xor(s2, off);
            sg += __shfl_xor(sg, off);
        }
        if (lane == 0) {
            float mu   = s1 * (1.f / 512.f);
            float var  = s2 * (1.f / 512.f) - mu * mu;
            float rstd = rsqrtf(var + 1e-5f);
            out[r0 + rr] = rstd * (sg - mu * sgw) + sbw + fcb0;
        }
    }
}

extern "C" void kernel_launch(void* const* d_in, const int* in_sizes, int n_in,
                              void* d_out, int out_size, void* d_ws, size_t ws_size,
                              hipStream_t stream)
{
    const float* Hin  = (const float*)d_in[0];
    const float* Ce   = (const float*)d_in[1];
    const float* w_ih = (const float*)d_in[2];
    const float* w_hh = (const float*)d_in[3];
    const float* b_ih = (const float*)d_in[4];
    const float* b_hh = (const float*)d_in[5];
    const float* fcmw = (const float*)d_in[6];
    const float* fcmb = (const float*)d_in[7];
    const float* lng  = (const float*)d_in[8];
    const float* lnb  = (const float*)d_in[9];
    const float* fcw  = (const float*)d_in[10];
    const float* fcb  = (const float*)d_in[11];
    float* out = (float*)d_out;

    // workspace layout (fp32 elems):
    //   xgc  : 8192*1536  = 12,582,912 f32 (50.3 MB)  time-chunk of xg
    //   hall : 32768*512  = 16,777,216 f32 (67.1 MB)
    //   W4hh : 786,432 f32 (3.1 MB)
    //   W4fc : 262,144 f32 (1.0 MB)
    // total ~121.6 MB
    float* ws     = (float*)d_ws;
    float* xgc    = ws;
    float* hall   = xgc + (size_t)B_ * TC_ * G_;
    float* w4hh_f = hall + (size_t)B_ * T_ * H_;
    float* w4fc_f = w4hh_f + (size_t)128 * G_ * 4;
    float4* W4hh  = (float4*)w4hh_f;
    float4* W4fc  = (float4*)w4fc_f;

    hipLaunchKernelGGL(k_prep, dim3(768), dim3(256), 0, stream, w_hh, fcmw, W4hh, W4fc);
    for (int c = 0; c < T_ / TC_; ++c) {
        hipLaunchKernelGGL(k_xg, dim3(12, 64), dim3(256), 0, stream,
                           Hin, Ce, w_ih, b_ih, xgc, c * TC_);
        for (int tc = 0; tc < TC_; ++tc)
            hipLaunchKernelGGL(k_step, dim3(32, 8), dim3(256), 0, stream,
                               W4hh, b_hh, xgc, hall, c * TC_ + tc);
    }
    hipLaunchKernelGGL(k_head, dim3(2048), dim3(256), 0, stream,
                       hall, W4fc, fcmb, lng, lnb, fcw, fcb, out);
}